// Round 19
// baseline (356.519 us; speedup 1.0000x reference)
//
#include <hip/hip_runtime.h>
#include <hip/hip_bf16.h>
#include <cstdint>
#include <cstddef>

#define NN 100000
#define DD 128
#define NE 1600000
#define NPB 196                 // nodes per bucket
#define NBUCK 511               // ceil(NN / NPB)
#define BCAP 6144               // LDS staging capacity per bucket
#define BUCKCAP 4608            // fixed packed/ssrc capacity per bucket (+26 sigma)
#define SCHUNK 8192             // edges per block-chunk in bscatter

// Device-pass-only builtin detection (host pass must NOT gate launches on this).
#if defined(__HIP_DEVICE_COMPILE__) && defined(__has_builtin)
# if __has_builtin(__builtin_amdgcn_cvt_pk_f32_fp8) && __has_builtin(__builtin_amdgcn_cvt_pk_fp8_f32)
#  define DEV_CVT8 1
# endif
#endif
#ifndef DEV_CVT8
# define DEV_CVT8 0
#endif

typedef short bf16x8 __attribute__((ext_vector_type(8)));
typedef float f32x4 __attribute__((ext_vector_type(4)));
typedef unsigned short u16;
typedef unsigned int u32;
typedef unsigned char u8;

__device__ inline float b2f(u16 u) {
    union { u32 i; float f; } c; c.i = ((u32)u) << 16; return c.f;
}
__device__ inline u16 f2b(float f) {
    __hip_bfloat16 h = __float2bfloat16(f);   // RNE
    return *reinterpret_cast<u16*>(&h);
}

// --- fp8 e4m3 software encode (input pre-scaled by 64; saturating) ----------
__device__ inline u32 enc1_fp8_sw(float v) {
    float a = fabsf(v);
    if (a > 448.0f) a = 448.0f;
    u32 sgn = (v < 0.0f) ? 0x80u : 0u;
    if (a < 0.015625f) {                 // below min normal 2^-6: quantum 2^-9
        int q = (int)rintf(a * 512.0f);  // q in [0,8]; q==8 -> byte 8 == e1m0
        return sgn | (u32)q;
    }
    int ex;
    float mant = frexpf(a, &ex);         // a = mant * 2^ex, mant in [0.5,1)
    int m = (int)rintf(mant * 16.0f) - 8;   // [0,8]
    int e = ex - 1 + 7;
    if (m == 8) { m = 0; e += 1; }
    if (e > 15) { e = 15; m = 6; }       // clamp to 448
    return sgn | ((u32)e << 3) | (u32)m;
}

__device__ inline u32 pack4_fp8(float a, float b, float c, float d) {
#if DEV_CVT8
    u32 r = 0;
    r = (u32)__builtin_amdgcn_cvt_pk_fp8_f32(a, b, (int)r, false);
    r = (u32)__builtin_amdgcn_cvt_pk_fp8_f32(c, d, (int)r, true);
    return r;
#else
    return enc1_fp8_sw(a) | (enc1_fp8_sw(b) << 8) | (enc1_fp8_sw(c) << 16)
         | (enc1_fp8_sw(d) << 24);
#endif
}

// --- fp8 decode helper (scaled domain; caller multiplies by 1/64) -----------
__device__ inline float dec1_fp8(u32 byte) {
    u32 lo = byte & 0x7Fu;
    union { u32 i; float f; } c;
    c.i = lo ? (((byte & 0x80u) << 24) | ((lo + 912u) << 20)) : 0u;
    return c.f;
}

// ---------------------------------------------------------------------------
// CSR build with FIXED-CAPACITY buckets (round-11 proven).
// ---------------------------------------------------------------------------
__global__ __launch_bounds__(256)
void initcur_kernel(int* __restrict__ cur) {
    int t = blockIdx.x * 256 + threadIdx.x;
    if (t < NBUCK) cur[t] = t * BUCKCAP;
}

__global__ __launch_bounds__(256)
void bscatter_kernel(const int* __restrict__ ei, int* __restrict__ cursor,
                     u32* __restrict__ packed, int n_edges) {
    __shared__ int hist[NBUCK];
    const int tid = threadIdx.x;
    const int nchunks = (n_edges + SCHUNK - 1) / SCHUNK;
    for (int ch = blockIdx.x; ch < nchunks; ch += gridDim.x) {
        const int e0 = ch * SCHUNK;
        const int e1 = min(e0 + SCHUNK, n_edges);
        for (int i = tid; i < NBUCK; i += 256) hist[i] = 0;
        __syncthreads();
        for (int e = e0 + tid; e < e1; e += 256)
            atomicAdd(&hist[ei[n_edges + e] / NPB], 1);
        __syncthreads();
        for (int i = tid; i < NBUCK; i += 256) {
            int c = hist[i];
            hist[i] = (c > 0) ? atomicAdd(&cursor[i], c) : 0;
        }
        __syncthreads();
        for (int e = e0 + tid; e < e1; e += 256) {
            int s = ei[e];
            int d = ei[n_edges + e];
            int b = d / NPB;
            int ld = d - b * NPB;
            int pos = atomicAdd(&hist[b], 1);
            packed[pos] = ((u32)ld << 17) | (u32)s;
        }
        __syncthreads();
    }
}

__global__ __launch_bounds__(256)
void blocal_kernel(const u32* __restrict__ packed, const int* __restrict__ cursor,
                   int* __restrict__ row_ptr, int* __restrict__ rpe,
                   int* __restrict__ ssrc) {
    __shared__ int out_s[BCAP];
    __shared__ int cur_s[NPB];
    __shared__ int excl_s[NPB];
    __shared__ int ws[4];
    __shared__ int wexc[4];

    const int b = blockIdx.x;
    const int tid = threadIdx.x;
    const int lane = tid & 63, wv = tid >> 6;
    const int pbase = b * BUCKCAP;
    const int cnt = cursor[b] - pbase;

    if (tid < NPB) cur_s[tid] = 0;
    __syncthreads();
    for (int i = tid; i < cnt; i += 256)
        atomicAdd(&cur_s[packed[pbase + i] >> 17], 1);
    __syncthreads();

    int v = (tid < NPB) ? cur_s[tid] : 0;
    int inc = v;
    #pragma unroll
    for (int o = 1; o < 64; o <<= 1) {
        int u = __shfl_up(inc, o);
        if (lane >= o) inc += u;
    }
    if (lane == 63) ws[wv] = inc;
    __syncthreads();
    if (tid == 0) {
        int s = 0;
        #pragma unroll
        for (int k = 0; k < 4; ++k) { wexc[k] = s; s += ws[k]; }
    }
    __syncthreads();
    int excl = inc - v + wexc[wv];
    if (tid < NPB) excl_s[tid] = excl;
    int gnode = b * NPB + tid;
    if (tid < NPB && gnode < NN) {
        row_ptr[gnode] = pbase + excl;
        rpe[gnode] = pbase + excl + v;
    }
    __syncthreads();
    if (tid < NPB) cur_s[tid] = excl_s[tid];
    __syncthreads();

    if (cnt <= BCAP) {
        for (int i = tid; i < cnt; i += 256) {
            u32 p = packed[pbase + i];
            int pos = atomicAdd(&cur_s[p >> 17], 1);
            out_s[pos] = (int)(p & 0x1FFFF);
        }
        __syncthreads();
        for (int i = tid; i < cnt; i += 256) ssrc[pbase + i] = out_s[i];
    } else {
        for (int i = tid; i < cnt; i += 256) {
            u32 p = packed[pbase + i];
            int pos = atomicAdd(&cur_s[p >> 17], 1);
            ssrc[pbase + pos] = (int)(p & 0x1FFFF);
        }
    }
}

// ---------------------------------------------------------------------------
// Conversions. x -> bf16 copy AND fp8(x*64) copy.
// ---------------------------------------------------------------------------
__global__ __launch_bounds__(256)
void cvt_x_kernel(const float* __restrict__ x, u16* __restrict__ xb,
                  u8* __restrict__ x8, long long n8) {
    long long t = (long long)blockIdx.x * blockDim.x + threadIdx.x;
    long long stride = (long long)gridDim.x * blockDim.x;
    for (; t < n8; t += stride) {
        float4 v0 = reinterpret_cast<const float4*>(x)[2 * t];
        float4 v1 = reinterpret_cast<const float4*>(x)[2 * t + 1];
        uint4 ob;
        ob.x = (u32)f2b(v0.x) | ((u32)f2b(v0.y) << 16);
        ob.y = (u32)f2b(v0.z) | ((u32)f2b(v0.w) << 16);
        ob.z = (u32)f2b(v1.x) | ((u32)f2b(v1.y) << 16);
        ob.w = (u32)f2b(v1.z) | ((u32)f2b(v1.w) << 16);
        reinterpret_cast<uint4*>(xb)[t] = ob;
        uint2 o8;
        o8.x = pack4_fp8(v0.x * 64.0f, v0.y * 64.0f, v0.z * 64.0f, v0.w * 64.0f);
        o8.y = pack4_fp8(v1.x * 64.0f, v1.y * 64.0f, v1.z * 64.0f, v1.w * 64.0f);
        reinterpret_cast<uint2*>(x8)[t] = o8;
    }
}

// bf16 h -> fp8(h*64) copy (for next layer's gather)
__global__ __launch_bounds__(256)
void cvt8_kernel(const u16* __restrict__ hb, u8* __restrict__ h8, int n8) {
    int t0 = blockIdx.x * 256 + threadIdx.x;
    int stride = gridDim.x * 256;
    for (int t = t0; t < n8; t += stride) {
        uint4 v = reinterpret_cast<const uint4*>(hb)[t];
        union { u32 i; float f; } c;
        float f0, f1, f2, f3, f4, f5, f6, f7;
        c.i = v.x << 16; f0 = c.f;  c.i = v.x & 0xffff0000u; f1 = c.f;
        c.i = v.y << 16; f2 = c.f;  c.i = v.y & 0xffff0000u; f3 = c.f;
        c.i = v.z << 16; f4 = c.f;  c.i = v.z & 0xffff0000u; f5 = c.f;
        c.i = v.w << 16; f6 = c.f;  c.i = v.w & 0xffff0000u; f7 = c.f;
        uint2 o;
        o.x = pack4_fp8(f0 * 64.0f, f1 * 64.0f, f2 * 64.0f, f3 * 64.0f);
        o.y = pack4_fp8(f4 * 64.0f, f5 * 64.0f, f6 * 64.0f, f7 * 64.0f);
        reinterpret_cast<uint2*>(h8)[t] = o;
    }
}

__global__ __launch_bounds__(256)
void cvt_w_kernel(const float* __restrict__ Wl, const float* __restrict__ Wr,
                  u16* __restrict__ Wcat) {
    int t = blockIdx.x * blockDim.x + threadIdx.x;
    const int NCAT = 3 * 128 * 256;
    if (t < NCAT) {
        int layer = t >> 15;
        int rem = t & 32767;
        int d = rem >> 8;
        int k = rem & 255;
        float v = (k < 128) ? Wl[layer * 16384 + d * 128 + k]
                            : Wr[layer * 16384 + d * 128 + (k - 128)];
        Wcat[t] = f2b(v);
    }
}

__global__ __launch_bounds__(256)
void wfuse_kernel(const float* __restrict__ W1f, const float* __restrict__ b1,
                  const float* __restrict__ W2, const float* __restrict__ b2,
                  u16* __restrict__ Wfb, float* __restrict__ bfuse) {
    int t = blockIdx.x * 256 + threadIdx.x;
    if (t < 48 * 128) {
        int l = t >> 7, k = t & 127;
        float s = 0.0f;
        if (l < 40) {
            for (int j = 0; j < 128; ++j)
                s += W2[l * 128 + j] * W1f[j * 128 + k];
        }
        Wfb[t] = f2b(s);
    }
    if (blockIdx.x == 0 && threadIdx.x < 40) {
        int l = threadIdx.x;
        float s = b2[l];
        for (int j = 0; j < 128; ++j) s += W2[l * 128 + j] * b1[j];
        bfuse[l] = s;
    }
}

// ---------------------------------------------------------------------------
// fp8 row decode-accumulate (8 bytes per lane)
// ---------------------------------------------------------------------------
#if DEV_CVT8
#define DEC8(q) do { \
    auto _p0 = __builtin_amdgcn_cvt_pk_f32_fp8((int)(q).x, false); \
    auto _p1 = __builtin_amdgcn_cvt_pk_f32_fp8((int)(q).x, true); \
    auto _p2 = __builtin_amdgcn_cvt_pk_f32_fp8((int)(q).y, false); \
    auto _p3 = __builtin_amdgcn_cvt_pk_f32_fp8((int)(q).y, true); \
    acc0 += _p0[0]; acc1 += _p0[1]; acc2 += _p1[0]; acc3 += _p1[1]; \
    acc4 += _p2[0]; acc5 += _p2[1]; acc6 += _p3[0]; acc7 += _p3[1]; \
} while (0)
#else
#define DEC8(q) do { \
    acc0 += dec1_fp8((q).x & 0xFFu); \
    acc1 += dec1_fp8(((q).x >> 8) & 0xFFu); \
    acc2 += dec1_fp8(((q).x >> 16) & 0xFFu); \
    acc3 += dec1_fp8((q).x >> 24); \
    acc4 += dec1_fp8((q).y & 0xFFu); \
    acc5 += dec1_fp8(((q).y >> 8) & 0xFFu); \
    acc6 += dec1_fp8(((q).y >> 16) & 0xFFu); \
    acc7 += dec1_fp8((q).y >> 24); \
} while (0)
#endif

// ---------------------------------------------------------------------------
// FUSED layer (r17-proven 64-strip structure) + deep-load gather fast path:
// when a 16-edge chunk is full, issue ALL 16 row-loads back-to-back (fully
// unrolled, constant-indexed regs) before decoding -- 4x more loads in
// flight during the latency-bound gather phase at low occupancy.
// ---------------------------------------------------------------------------
__global__ __launch_bounds__(256)
void fused_layer(const u16* __restrict__ hin, const u8* __restrict__ h8,
                 const int* __restrict__ rp, const int* __restrict__ rpe,
                 const int* __restrict__ ssrc, const u16* __restrict__ Wc,
                 const float* __restrict__ b1, const float* __restrict__ b2,
                 u16* __restrict__ out, int n_nodes) {
    __shared__ __attribute__((aligned(16))) char a_s[64 * 512];  // 32 KB
    __shared__ float red_s[64][4];

    const int tid = threadIdx.x;
    const int w = tid >> 6;
    const int l = tid & 63;
    const int q = l >> 4;       // group id within wave
    const int c16 = l & 15;

    const int base = blockIdx.x * 64;

    // ---- stage h half: 64 rows x 16 chunks of 16B ----
    for (int ci = tid; ci < 1024; ci += 256) {
        int r = ci >> 4, c = ci & 15;
        int node = base + r;
        uint4 v = {0, 0, 0, 0};
        if (node < n_nodes)
            v = *reinterpret_cast<const uint4*>(hin + (size_t)node * DD + c * 8);
        *reinterpret_cast<uint4*>(a_s + r * 512 + ((c ^ (r & 7)) * 16)) = v;
    }

    // ---- gather prop half directly into LDS ----
    {
        const int gb = l & 48;       // group base lane (q*16)
        const int cl = c16;          // lane within group = byte-chunk of row
        const float us = 0.015625f;  // 1/64 unscale
        for (int pass = 0; pass < 4; ++pass) {
            int r = w * 16 + pass * 4 + q;
            int n = min(base + r, n_nodes - 1);
            int beg = rp[n];
            int deg = rpe[n] - beg;
            float acc0 = 0, acc1 = 0, acc2 = 0, acc3 = 0;
            float acc4 = 0, acc5 = 0, acc6 = 0, acc7 = 0;
            for (int c0 = 0; c0 < deg; c0 += 16) {   // uniform per group
                int rem = deg - c0;
                int sv = (cl < rem) ? ssrc[beg + c0 + cl] : 0;
                if (rem >= 16) {
                    // fast path: 16 loads in flight before any decode
                    uint2 vv[16];
                    #pragma unroll
                    for (int k = 0; k < 16; ++k) {
                        int s = __shfl(sv, gb | k);
                        vv[k] = *reinterpret_cast<const uint2*>(
                            h8 + (size_t)s * 128 + cl * 8);
                    }
                    #pragma unroll
                    for (int k = 0; k < 16; ++k) DEC8(vv[k]);
                } else {
                    #pragma unroll
                    for (int k = 0; k < 16; k += 4) {
                        if (k >= rem) break;
                        int s0 = __shfl(sv, gb | k);
                        int s1 = __shfl(sv, gb | (k + 1));
                        int s2 = __shfl(sv, gb | (k + 2));
                        int s3 = __shfl(sv, gb | (k + 3));
                        uint2 v0, v1 = {0, 0}, v2 = {0, 0}, v3 = {0, 0};
                        v0 = *reinterpret_cast<const uint2*>(h8 + (size_t)s0 * 128 + cl * 8);
                        if (k + 1 < rem)
                            v1 = *reinterpret_cast<const uint2*>(h8 + (size_t)s1 * 128 + cl * 8);
                        if (k + 2 < rem)
                            v2 = *reinterpret_cast<const uint2*>(h8 + (size_t)s2 * 128 + cl * 8);
                        if (k + 3 < rem)
                            v3 = *reinterpret_cast<const uint2*>(h8 + (size_t)s3 * 128 + cl * 8);
                        DEC8(v0);
                        DEC8(v1);
                        DEC8(v2);
                        DEC8(v3);
                    }
                }
            }
            uint4 o;
            o.x = (u32)f2b(acc0 * us) | ((u32)f2b(acc1 * us) << 16);
            o.y = (u32)f2b(acc2 * us) | ((u32)f2b(acc3 * us) << 16);
            o.z = (u32)f2b(acc4 * us) | ((u32)f2b(acc5 * us) << 16);
            o.w = (u32)f2b(acc6 * us) | ((u32)f2b(acc7 * us) << 16);
            *reinterpret_cast<uint4*>(
                a_s + r * 512 + (((16 + cl) ^ (r & 7)) * 16)) = o;
        }
    }
    __syncthreads();

    // ---- B fragments (loaded post-gather; L2-hot Wcat) ----
    bf16x8 bfrag[2][8];
    int col[2];
    float bias[2];
    #pragma unroll
    for (int t = 0; t < 2; ++t) {
        col[t] = w * 32 + t * 16 + c16;
        bias[t] = b1[col[t]] + b2[col[t]];
        #pragma unroll
        for (int kk = 0; kk < 8; ++kk)
            bfrag[t][kk] = *reinterpret_cast<const bf16x8*>(
                Wc + (size_t)col[t] * 256 + kk * 32 + q * 8);
    }

    // ---- MFMA (r13-proven) ----
    f32x4 acc[4][2] = {};
    #pragma unroll
    for (int kk = 0; kk < 8; ++kk) {
        int cc = kk * 4 + q;
        #pragma unroll
        for (int m = 0; m < 4; ++m) {
            int row = m * 16 + c16;
            bf16x8 a = *reinterpret_cast<const bf16x8*>(
                a_s + row * 512 + ((cc ^ (row & 7)) * 16));
            acc[m][0] = __builtin_amdgcn_mfma_f32_16x16x32_bf16(a, bfrag[0][kk], acc[m][0], 0, 0, 0);
            acc[m][1] = __builtin_amdgcn_mfma_f32_16x16x32_bf16(a, bfrag[1][kk], acc[m][1], 0, 0, 0);
        }
    }

    // ---- normalize + ReLU (r13-proven epilogue) ----
    float vals[4][2][4];
    float ss[4][4];
    #pragma unroll
    for (int m = 0; m < 4; ++m) {
        #pragma unroll
        for (int reg = 0; reg < 4; ++reg) {
            float s = 0.0f;
            #pragma unroll
            for (int t = 0; t < 2; ++t) {
                float v = acc[m][t][reg] + bias[t];
                vals[m][t][reg] = v;
                s += v * v;
            }
            s += __shfl_xor(s, 1);
            s += __shfl_xor(s, 2);
            s += __shfl_xor(s, 4);
            s += __shfl_xor(s, 8);
            ss[m][reg] = s;
        }
    }
    if (c16 == 0) {
        #pragma unroll
        for (int m = 0; m < 4; ++m)
            #pragma unroll
            for (int reg = 0; reg < 4; ++reg)
                red_s[m * 16 + q * 4 + reg][w] = ss[m][reg];
    }
    __syncthreads();
    #pragma unroll
    for (int m = 0; m < 4; ++m) {
        #pragma unroll
        for (int reg = 0; reg < 4; ++reg) {
            int row = m * 16 + q * 4 + reg;
            float4 rr = *reinterpret_cast<float4*>(&red_s[row][0]);
            float tot = rr.x + rr.y + rr.z + rr.w;
            float rn = 1.0f / fmaxf(sqrtf(tot), 1e-12f);
            if (base + row < n_nodes) {
                #pragma unroll
                for (int t = 0; t < 2; ++t) {
                    float v = fmaxf(vals[m][t][reg] * rn, 0.0f);
                    out[(size_t)(base + row) * DD + col[t]] = f2b(v);
                }
            }
        }
    }
}

// ---------------------------------------------------------------------------
// Fused post stage: out = log_softmax(h @ Wfuse^T + bfuse), 40 classes.
// ---------------------------------------------------------------------------
__global__ __launch_bounds__(256)
void postfused_kernel(const u16* __restrict__ hin, const u16* __restrict__ Wfb,
                      const float* __restrict__ bfuse, float* __restrict__ out,
                      int n_nodes) {
    __shared__ char a_s[64 * 256];
    const int tid = threadIdx.x;
    const int w = tid >> 6;
    const int l = tid & 63;
    const int q = l >> 4;
    const int c16 = l & 15;

    bf16x8 bfrag[3][4];
    float bias[3];
    int col[3];
    #pragma unroll
    for (int t = 0; t < 3; ++t) {
        col[t] = t * 16 + c16;
        bias[t] = (col[t] < 40) ? bfuse[col[t]] : 0.0f;
        #pragma unroll
        for (int kk = 0; kk < 4; ++kk)
            bfrag[t][kk] = *reinterpret_cast<const bf16x8*>(
                Wfb + col[t] * 128 + kk * 32 + q * 8);
    }

    const int base = blockIdx.x * 64;

    for (int ci = tid; ci < 1024; ci += 256) {
        int r = ci >> 4, c = ci & 15;
        uint4 v = {0, 0, 0, 0};
        if (base + r < n_nodes)
            v = *reinterpret_cast<const uint4*>(hin + (size_t)(base + r) * DD + c * 8);
        *reinterpret_cast<uint4*>(a_s + r * 256 + ((c ^ (r & 7)) * 16)) = v;
    }
    __syncthreads();

    f32x4 acc[3] = {};
    const int arow = w * 16 + c16;
    #pragma unroll
    for (int kk = 0; kk < 4; ++kk) {
        int cc = kk * 4 + q;
        bf16x8 a = *reinterpret_cast<const bf16x8*>(
            a_s + arow * 256 + ((cc ^ (arow & 7)) * 16));
        acc[0] = __builtin_amdgcn_mfma_f32_16x16x32_bf16(a, bfrag[0][kk], acc[0], 0, 0, 0);
        acc[1] = __builtin_amdgcn_mfma_f32_16x16x32_bf16(a, bfrag[1][kk], acc[1], 0, 0, 0);
        acc[2] = __builtin_amdgcn_mfma_f32_16x16x32_bf16(a, bfrag[2][kk], acc[2], 0, 0, 0);
    }

    #pragma unroll
    for (int reg = 0; reg < 4; ++reg) {
        int row = base + w * 16 + q * 4 + reg;
        float v[3];
        float m = -INFINITY;
        #pragma unroll
        for (int t = 0; t < 3; ++t) {
            v[t] = acc[t][reg] + bias[t];
            if (col[t] < 40) m = fmaxf(m, v[t]);
        }
        m = fmaxf(m, __shfl_xor(m, 1));
        m = fmaxf(m, __shfl_xor(m, 2));
        m = fmaxf(m, __shfl_xor(m, 4));
        m = fmaxf(m, __shfl_xor(m, 8));
        float s = 0.0f;
        #pragma unroll
        for (int t = 0; t < 3; ++t)
            if (col[t] < 40) s += expf(v[t] - m);
        s += __shfl_xor(s, 1);
        s += __shfl_xor(s, 2);
        s += __shfl_xor(s, 4);
        s += __shfl_xor(s, 8);
        float lg = logf(s);
        if (row < n_nodes) {
            #pragma unroll
            for (int t = 0; t < 3; ++t)
                if (col[t] < 40)
                    out[(size_t)row * 40 + col[t]] = v[t] - m - lg;
        }
    }
}

// ---------------------------------------------------------------------------
extern "C" void kernel_launch(void* const* d_in, const int* in_sizes, int n_in,
                              void* d_out, int out_size, void* d_ws, size_t ws_size,
                              hipStream_t stream) {
    const float* x   = (const float*)d_in[0];
    const int*   ei  = (const int*)d_in[1];
    const float* Wl  = (const float*)d_in[2];
    const float* bl  = (const float*)d_in[3];
    const float* Wr  = (const float*)d_in[4];
    const float* br  = (const float*)d_in[5];
    const float* W1f = (const float*)d_in[6];
    const float* b1  = (const float*)d_in[7];
    const float* W2  = (const float*)d_in[8];
    const float* b2  = (const float*)d_in[9];
    float* outp = (float*)d_out;

    // Workspace: xb | P(unused) | bufA | bufB | h8 | Wcat | Wfb+bfuse |
    //            cursor | row_ptr | rpe | ssrc(padded) | packed(padded)
    u16* xb   = (u16*)d_ws;
    u16* P    = xb + (size_t)NN * DD;
    u16* bufA = P + (size_t)NN * DD;
    u16* bufB = bufA + (size_t)NN * DD;
    u8*  h8   = (u8*)(bufB + (size_t)NN * DD);
    u16* Wcat = (u16*)(h8 + (size_t)NN * 128);
    u16* Wfb  = Wcat + 3 * 128 * 256;
    float* bfuse = (float*)(Wfb + 8192);
    int* cursor  = (int*)(Wfb + 128 * 128);
    int* row_ptr = cursor + NBUCK + 1;
    int* rpe     = row_ptr + NN;
    int* ssrc    = rpe + NN;
    u32* packed  = (u32*)(ssrc + NBUCK * BUCKCAP);

    // CSR build: fixed-capacity buckets
    initcur_kernel<<<2, 256, 0, stream>>>(cursor);
    bscatter_kernel<<<(NE + SCHUNK - 1) / SCHUNK, 256, 0, stream>>>(
        ei, cursor, packed, NE);
    blocal_kernel<<<NBUCK, 256, 0, stream>>>(packed, cursor, row_ptr, rpe, ssrc);

    // Conversions + algebraic post-fusion precompute
    cvt_x_kernel<<<6250, 256, 0, stream>>>(x, xb, h8, (long long)NN * DD / 8);
    cvt_w_kernel<<<(3 * 128 * 256 + 255) / 256, 256, 0, stream>>>(Wl, Wr, Wcat);
    wfuse_kernel<<<24, 256, 0, stream>>>(W1f, b1, W2, b2, Wfb, bfuse);

    const int n_strips64 = (NN + 63) / 64;   // 1563
    const int n8 = NN * DD / 8;

    const u16* hcur = xb;
    u16* hnext;
    for (int i = 0; i < 3; ++i) {
        hnext = (i == 0) ? bufA : ((hcur == bufA) ? bufB : bufA);
        fused_layer<<<n_strips64, 256, 0, stream>>>(
            hcur, h8, row_ptr, rpe, ssrc, Wcat + (size_t)i * 128 * 256,
            bl + (size_t)i * DD, br + (size_t)i * DD, hnext, NN);
        if (i < 2)   // next layer's gather needs fp8 copy of hnext
            cvt8_kernel<<<2048, 256, 0, stream>>>(hnext, h8, n8);
        hcur = hnext;
    }
    // Fused post1+post2+log_softmax
    postfused_kernel<<<n_strips64, 256, 0, stream>>>(hcur, Wfb, bfuse, outp, NN);
}

// Round 20
// 290.095 us; speedup vs baseline: 1.2290x; 1.2290x over previous
//
#include <hip/hip_runtime.h>
#include <hip/hip_bf16.h>
#include <cstdint>
#include <cstddef>

#define NN 100000
#define DD 128
#define NE 1600000
#define NPB 196                 // nodes per bucket
#define NBUCK 511               // ceil(NN / NPB)
#define BCAP 6144               // LDS staging capacity per bucket
#define BUCKCAP 4608            // fixed packed/ssrc capacity per bucket (+26 sigma)
#define SCHUNK 8192             // edges per block-chunk in bscatter

// Device-pass-only builtin detection (host pass must NOT gate launches on this).
#if defined(__HIP_DEVICE_COMPILE__) && defined(__has_builtin)
# if __has_builtin(__builtin_amdgcn_cvt_pk_f32_fp8) && __has_builtin(__builtin_amdgcn_cvt_pk_fp8_f32)
#  define DEV_CVT8 1
# endif
#endif
#ifndef DEV_CVT8
# define DEV_CVT8 0
#endif

typedef short bf16x8 __attribute__((ext_vector_type(8)));
typedef float f32x4 __attribute__((ext_vector_type(4)));
typedef unsigned short u16;
typedef unsigned int u32;
typedef unsigned char u8;

__device__ inline float b2f(u16 u) {
    union { u32 i; float f; } c; c.i = ((u32)u) << 16; return c.f;
}
__device__ inline u16 f2b(float f) {
    __hip_bfloat16 h = __float2bfloat16(f);   // RNE
    return *reinterpret_cast<u16*>(&h);
}

// --- fp8 e4m3 software encode (input pre-scaled by 64; saturating) ----------
__device__ inline u32 enc1_fp8_sw(float v) {
    float a = fabsf(v);
    if (a > 448.0f) a = 448.0f;
    u32 sgn = (v < 0.0f) ? 0x80u : 0u;
    if (a < 0.015625f) {                 // below min normal 2^-6: quantum 2^-9
        int q = (int)rintf(a * 512.0f);  // q in [0,8]; q==8 -> byte 8 == e1m0
        return sgn | (u32)q;
    }
    int ex;
    float mant = frexpf(a, &ex);         // a = mant * 2^ex, mant in [0.5,1)
    int m = (int)rintf(mant * 16.0f) - 8;   // [0,8]
    int e = ex - 1 + 7;
    if (m == 8) { m = 0; e += 1; }
    if (e > 15) { e = 15; m = 6; }       // clamp to 448
    return sgn | ((u32)e << 3) | (u32)m;
}

__device__ inline u32 pack4_fp8(float a, float b, float c, float d) {
#if DEV_CVT8
    u32 r = 0;
    r = (u32)__builtin_amdgcn_cvt_pk_fp8_f32(a, b, (int)r, false);
    r = (u32)__builtin_amdgcn_cvt_pk_fp8_f32(c, d, (int)r, true);
    return r;
#else
    return enc1_fp8_sw(a) | (enc1_fp8_sw(b) << 8) | (enc1_fp8_sw(c) << 16)
         | (enc1_fp8_sw(d) << 24);
#endif
}

// --- fp8 decode helper (scaled domain; caller multiplies by 1/64) -----------
__device__ inline float dec1_fp8(u32 byte) {
    u32 lo = byte & 0x7Fu;
    union { u32 i; float f; } c;
    c.i = lo ? (((byte & 0x80u) << 24) | ((lo + 912u) << 20)) : 0u;
    return c.f;
}

// ---------------------------------------------------------------------------
// CSR build with FIXED-CAPACITY buckets (round-11 proven).
// ---------------------------------------------------------------------------
__global__ __launch_bounds__(256)
void initcur_kernel(int* __restrict__ cur) {
    int t = blockIdx.x * 256 + threadIdx.x;
    if (t < NBUCK) cur[t] = t * BUCKCAP;
}

__global__ __launch_bounds__(256)
void bscatter_kernel(const int* __restrict__ ei, int* __restrict__ cursor,
                     u32* __restrict__ packed, int n_edges) {
    __shared__ int hist[NBUCK];
    const int tid = threadIdx.x;
    const int nchunks = (n_edges + SCHUNK - 1) / SCHUNK;
    for (int ch = blockIdx.x; ch < nchunks; ch += gridDim.x) {
        const int e0 = ch * SCHUNK;
        const int e1 = min(e0 + SCHUNK, n_edges);
        for (int i = tid; i < NBUCK; i += 256) hist[i] = 0;
        __syncthreads();
        for (int e = e0 + tid; e < e1; e += 256)
            atomicAdd(&hist[ei[n_edges + e] / NPB], 1);
        __syncthreads();
        for (int i = tid; i < NBUCK; i += 256) {
            int c = hist[i];
            hist[i] = (c > 0) ? atomicAdd(&cursor[i], c) : 0;
        }
        __syncthreads();
        for (int e = e0 + tid; e < e1; e += 256) {
            int s = ei[e];
            int d = ei[n_edges + e];
            int b = d / NPB;
            int ld = d - b * NPB;
            int pos = atomicAdd(&hist[b], 1);
            packed[pos] = ((u32)ld << 17) | (u32)s;
        }
        __syncthreads();
    }
}

__global__ __launch_bounds__(256)
void blocal_kernel(const u32* __restrict__ packed, const int* __restrict__ cursor,
                   int* __restrict__ row_ptr, int* __restrict__ rpe,
                   int* __restrict__ ssrc) {
    __shared__ int out_s[BCAP];
    __shared__ int cur_s[NPB];
    __shared__ int excl_s[NPB];
    __shared__ int ws[4];
    __shared__ int wexc[4];

    const int b = blockIdx.x;
    const int tid = threadIdx.x;
    const int lane = tid & 63, wv = tid >> 6;
    const int pbase = b * BUCKCAP;
    const int cnt = cursor[b] - pbase;

    if (tid < NPB) cur_s[tid] = 0;
    __syncthreads();
    for (int i = tid; i < cnt; i += 256)
        atomicAdd(&cur_s[packed[pbase + i] >> 17], 1);
    __syncthreads();

    int v = (tid < NPB) ? cur_s[tid] : 0;
    int inc = v;
    #pragma unroll
    for (int o = 1; o < 64; o <<= 1) {
        int u = __shfl_up(inc, o);
        if (lane >= o) inc += u;
    }
    if (lane == 63) ws[wv] = inc;
    __syncthreads();
    if (tid == 0) {
        int s = 0;
        #pragma unroll
        for (int k = 0; k < 4; ++k) { wexc[k] = s; s += ws[k]; }
    }
    __syncthreads();
    int excl = inc - v + wexc[wv];
    if (tid < NPB) excl_s[tid] = excl;
    int gnode = b * NPB + tid;
    if (tid < NPB && gnode < NN) {
        row_ptr[gnode] = pbase + excl;
        rpe[gnode] = pbase + excl + v;
    }
    __syncthreads();
    if (tid < NPB) cur_s[tid] = excl_s[tid];
    __syncthreads();

    if (cnt <= BCAP) {
        for (int i = tid; i < cnt; i += 256) {
            u32 p = packed[pbase + i];
            int pos = atomicAdd(&cur_s[p >> 17], 1);
            out_s[pos] = (int)(p & 0x1FFFF);
        }
        __syncthreads();
        for (int i = tid; i < cnt; i += 256) ssrc[pbase + i] = out_s[i];
    } else {
        for (int i = tid; i < cnt; i += 256) {
            u32 p = packed[pbase + i];
            int pos = atomicAdd(&cur_s[p >> 17], 1);
            ssrc[pbase + pos] = (int)(p & 0x1FFFF);
        }
    }
}

// ---------------------------------------------------------------------------
// Conversions. x -> bf16 copy AND fp8(x*64) copy.
// ---------------------------------------------------------------------------
__global__ __launch_bounds__(256)
void cvt_x_kernel(const float* __restrict__ x, u16* __restrict__ xb,
                  u8* __restrict__ x8, long long n8) {
    long long t = (long long)blockIdx.x * blockDim.x + threadIdx.x;
    long long stride = (long long)gridDim.x * blockDim.x;
    for (; t < n8; t += stride) {
        float4 v0 = reinterpret_cast<const float4*>(x)[2 * t];
        float4 v1 = reinterpret_cast<const float4*>(x)[2 * t + 1];
        uint4 ob;
        ob.x = (u32)f2b(v0.x) | ((u32)f2b(v0.y) << 16);
        ob.y = (u32)f2b(v0.z) | ((u32)f2b(v0.w) << 16);
        ob.z = (u32)f2b(v1.x) | ((u32)f2b(v1.y) << 16);
        ob.w = (u32)f2b(v1.z) | ((u32)f2b(v1.w) << 16);
        reinterpret_cast<uint4*>(xb)[t] = ob;
        uint2 o8;
        o8.x = pack4_fp8(v0.x * 64.0f, v0.y * 64.0f, v0.z * 64.0f, v0.w * 64.0f);
        o8.y = pack4_fp8(v1.x * 64.0f, v1.y * 64.0f, v1.z * 64.0f, v1.w * 64.0f);
        reinterpret_cast<uint2*>(x8)[t] = o8;
    }
}

// bf16 h -> fp8(h*64) copy (for next layer's gather)
__global__ __launch_bounds__(256)
void cvt8_kernel(const u16* __restrict__ hb, u8* __restrict__ h8, int n8) {
    int t0 = blockIdx.x * 256 + threadIdx.x;
    int stride = gridDim.x * 256;
    for (int t = t0; t < n8; t += stride) {
        uint4 v = reinterpret_cast<const uint4*>(hb)[t];
        union { u32 i; float f; } c;
        float f0, f1, f2, f3, f4, f5, f6, f7;
        c.i = v.x << 16; f0 = c.f;  c.i = v.x & 0xffff0000u; f1 = c.f;
        c.i = v.y << 16; f2 = c.f;  c.i = v.y & 0xffff0000u; f3 = c.f;
        c.i = v.z << 16; f4 = c.f;  c.i = v.z & 0xffff0000u; f5 = c.f;
        c.i = v.w << 16; f6 = c.f;  c.i = v.w & 0xffff0000u; f7 = c.f;
        uint2 o;
        o.x = pack4_fp8(f0 * 64.0f, f1 * 64.0f, f2 * 64.0f, f3 * 64.0f);
        o.y = pack4_fp8(f4 * 64.0f, f5 * 64.0f, f6 * 64.0f, f7 * 64.0f);
        reinterpret_cast<uint2*>(h8)[t] = o;
    }
}

__global__ __launch_bounds__(256)
void cvt_w_kernel(const float* __restrict__ Wl, const float* __restrict__ Wr,
                  u16* __restrict__ Wcat) {
    int t = blockIdx.x * blockDim.x + threadIdx.x;
    const int NCAT = 3 * 128 * 256;
    if (t < NCAT) {
        int layer = t >> 15;
        int rem = t & 32767;
        int d = rem >> 8;
        int k = rem & 255;
        float v = (k < 128) ? Wl[layer * 16384 + d * 128 + k]
                            : Wr[layer * 16384 + d * 128 + (k - 128)];
        Wcat[t] = f2b(v);
    }
}

__global__ __launch_bounds__(256)
void wfuse_kernel(const float* __restrict__ W1f, const float* __restrict__ b1,
                  const float* __restrict__ W2, const float* __restrict__ b2,
                  u16* __restrict__ Wfb, float* __restrict__ bfuse) {
    int t = blockIdx.x * 256 + threadIdx.x;
    if (t < 48 * 128) {
        int l = t >> 7, k = t & 127;
        float s = 0.0f;
        if (l < 40) {
            for (int j = 0; j < 128; ++j)
                s += W2[l * 128 + j] * W1f[j * 128 + k];
        }
        Wfb[t] = f2b(s);
    }
    if (blockIdx.x == 0 && threadIdx.x < 40) {
        int l = threadIdx.x;
        float s = b2[l];
        for (int j = 0; j < 128; ++j) s += W2[l * 128 + j] * b1[j];
        bfuse[l] = s;
    }
}

// ---------------------------------------------------------------------------
// fp8 row decode-accumulate (8 bytes per lane)
// ---------------------------------------------------------------------------
#if DEV_CVT8
#define DEC8(q) do { \
    auto _p0 = __builtin_amdgcn_cvt_pk_f32_fp8((int)(q).x, false); \
    auto _p1 = __builtin_amdgcn_cvt_pk_f32_fp8((int)(q).x, true); \
    auto _p2 = __builtin_amdgcn_cvt_pk_f32_fp8((int)(q).y, false); \
    auto _p3 = __builtin_amdgcn_cvt_pk_f32_fp8((int)(q).y, true); \
    acc0 += _p0[0]; acc1 += _p0[1]; acc2 += _p1[0]; acc3 += _p1[1]; \
    acc4 += _p2[0]; acc5 += _p2[1]; acc6 += _p3[0]; acc7 += _p3[1]; \
} while (0)
#else
#define DEC8(q) do { \
    acc0 += dec1_fp8((q).x & 0xFFu); \
    acc1 += dec1_fp8(((q).x >> 8) & 0xFFu); \
    acc2 += dec1_fp8(((q).x >> 16) & 0xFFu); \
    acc3 += dec1_fp8((q).x >> 24); \
    acc4 += dec1_fp8((q).y & 0xFFu); \
    acc5 += dec1_fp8(((q).y >> 8) & 0xFFu); \
    acc6 += dec1_fp8(((q).y >> 16) & 0xFFu); \
    acc7 += dec1_fp8((q).y >> 24); \
} while (0)
#endif

// ---------------------------------------------------------------------------
// FUSED layer (r17-proven, 291 us): CSR gather (fp8) -> LDS prop half ->
// MFMA -> norm -> ReLU. 256 thr = 4 waves, 64-node strip. Gather: 16-lane
// group per node, 4 passes of 4 rows/wave, 4-load blocks in flight,
// B-frags loaded AFTER the gather.
// ---------------------------------------------------------------------------
__global__ __launch_bounds__(256)
void fused_layer(const u16* __restrict__ hin, const u8* __restrict__ h8,
                 const int* __restrict__ rp, const int* __restrict__ rpe,
                 const int* __restrict__ ssrc, const u16* __restrict__ Wc,
                 const float* __restrict__ b1, const float* __restrict__ b2,
                 u16* __restrict__ out, int n_nodes) {
    __shared__ __attribute__((aligned(16))) char a_s[64 * 512];  // 32 KB
    __shared__ float red_s[64][4];

    const int tid = threadIdx.x;
    const int w = tid >> 6;
    const int l = tid & 63;
    const int q = l >> 4;       // group id within wave
    const int c16 = l & 15;

    const int base = blockIdx.x * 64;

    // ---- stage h half: 64 rows x 16 chunks of 16B ----
    for (int ci = tid; ci < 1024; ci += 256) {
        int r = ci >> 4, c = ci & 15;
        int node = base + r;
        uint4 v = {0, 0, 0, 0};
        if (node < n_nodes)
            v = *reinterpret_cast<const uint4*>(hin + (size_t)node * DD + c * 8);
        *reinterpret_cast<uint4*>(a_s + r * 512 + ((c ^ (r & 7)) * 16)) = v;
    }

    // ---- gather prop half directly into LDS ----
    {
        const int gb = l & 48;       // group base lane (q*16)
        const int cl = c16;          // lane within group = byte-chunk of row
        const float us = 0.015625f;  // 1/64 unscale
        for (int pass = 0; pass < 4; ++pass) {
            int r = w * 16 + pass * 4 + q;
            int n = min(base + r, n_nodes - 1);
            int beg = rp[n];
            int deg = rpe[n] - beg;
            float acc0 = 0, acc1 = 0, acc2 = 0, acc3 = 0;
            float acc4 = 0, acc5 = 0, acc6 = 0, acc7 = 0;
            for (int c0 = 0; c0 < deg; c0 += 16) {   // uniform per group
                int rem = deg - c0;
                int sv = (cl < rem) ? ssrc[beg + c0 + cl] : 0;
                #pragma unroll
                for (int k = 0; k < 16; k += 4) {
                    if (k >= rem) break;
                    int s0 = __shfl(sv, gb | k);
                    int s1 = __shfl(sv, gb | (k + 1));
                    int s2 = __shfl(sv, gb | (k + 2));
                    int s3 = __shfl(sv, gb | (k + 3));
                    uint2 v0, v1 = {0, 0}, v2 = {0, 0}, v3 = {0, 0};
                    v0 = *reinterpret_cast<const uint2*>(h8 + (size_t)s0 * 128 + cl * 8);
                    if (k + 1 < rem)
                        v1 = *reinterpret_cast<const uint2*>(h8 + (size_t)s1 * 128 + cl * 8);
                    if (k + 2 < rem)
                        v2 = *reinterpret_cast<const uint2*>(h8 + (size_t)s2 * 128 + cl * 8);
                    if (k + 3 < rem)
                        v3 = *reinterpret_cast<const uint2*>(h8 + (size_t)s3 * 128 + cl * 8);
                    DEC8(v0);
                    DEC8(v1);
                    DEC8(v2);
                    DEC8(v3);
                }
            }
            uint4 o;
            o.x = (u32)f2b(acc0 * us) | ((u32)f2b(acc1 * us) << 16);
            o.y = (u32)f2b(acc2 * us) | ((u32)f2b(acc3 * us) << 16);
            o.z = (u32)f2b(acc4 * us) | ((u32)f2b(acc5 * us) << 16);
            o.w = (u32)f2b(acc6 * us) | ((u32)f2b(acc7 * us) << 16);
            *reinterpret_cast<uint4*>(
                a_s + r * 512 + (((16 + cl) ^ (r & 7)) * 16)) = o;
        }
    }
    __syncthreads();

    // ---- B fragments (loaded post-gather; L2-hot Wcat) ----
    bf16x8 bfrag[2][8];
    int col[2];
    float bias[2];
    #pragma unroll
    for (int t = 0; t < 2; ++t) {
        col[t] = w * 32 + t * 16 + c16;
        bias[t] = b1[col[t]] + b2[col[t]];
        #pragma unroll
        for (int kk = 0; kk < 8; ++kk)
            bfrag[t][kk] = *reinterpret_cast<const bf16x8*>(
                Wc + (size_t)col[t] * 256 + kk * 32 + q * 8);
    }

    // ---- MFMA (r13-proven) ----
    f32x4 acc[4][2] = {};
    #pragma unroll
    for (int kk = 0; kk < 8; ++kk) {
        int cc = kk * 4 + q;
        #pragma unroll
        for (int m = 0; m < 4; ++m) {
            int row = m * 16 + c16;
            bf16x8 a = *reinterpret_cast<const bf16x8*>(
                a_s + row * 512 + ((cc ^ (row & 7)) * 16));
            acc[m][0] = __builtin_amdgcn_mfma_f32_16x16x32_bf16(a, bfrag[0][kk], acc[m][0], 0, 0, 0);
            acc[m][1] = __builtin_amdgcn_mfma_f32_16x16x32_bf16(a, bfrag[1][kk], acc[m][1], 0, 0, 0);
        }
    }

    // ---- normalize + ReLU (r13-proven epilogue) ----
    float vals[4][2][4];
    float ss[4][4];
    #pragma unroll
    for (int m = 0; m < 4; ++m) {
        #pragma unroll
        for (int reg = 0; reg < 4; ++reg) {
            float s = 0.0f;
            #pragma unroll
            for (int t = 0; t < 2; ++t) {
                float v = acc[m][t][reg] + bias[t];
                vals[m][t][reg] = v;
                s += v * v;
            }
            s += __shfl_xor(s, 1);
            s += __shfl_xor(s, 2);
            s += __shfl_xor(s, 4);
            s += __shfl_xor(s, 8);
            ss[m][reg] = s;
        }
    }
    if (c16 == 0) {
        #pragma unroll
        for (int m = 0; m < 4; ++m)
            #pragma unroll
            for (int reg = 0; reg < 4; ++reg)
                red_s[m * 16 + q * 4 + reg][w] = ss[m][reg];
    }
    __syncthreads();
    #pragma unroll
    for (int m = 0; m < 4; ++m) {
        #pragma unroll
        for (int reg = 0; reg < 4; ++reg) {
            int row = m * 16 + q * 4 + reg;
            float4 rr = *reinterpret_cast<float4*>(&red_s[row][0]);
            float tot = rr.x + rr.y + rr.z + rr.w;
            float rn = 1.0f / fmaxf(sqrtf(tot), 1e-12f);
            if (base + row < n_nodes) {
                #pragma unroll
                for (int t = 0; t < 2; ++t) {
                    float v = fmaxf(vals[m][t][reg] * rn, 0.0f);
                    out[(size_t)(base + row) * DD + col[t]] = f2b(v);
                }
            }
        }
    }
}

// ---------------------------------------------------------------------------
// Fused post stage: out = log_softmax(h @ Wfuse^T + bfuse), 40 classes.
// ---------------------------------------------------------------------------
__global__ __launch_bounds__(256)
void postfused_kernel(const u16* __restrict__ hin, const u16* __restrict__ Wfb,
                      const float* __restrict__ bfuse, float* __restrict__ out,
                      int n_nodes) {
    __shared__ char a_s[64 * 256];
    const int tid = threadIdx.x;
    const int w = tid >> 6;
    const int l = tid & 63;
    const int q = l >> 4;
    const int c16 = l & 15;

    bf16x8 bfrag[3][4];
    float bias[3];
    int col[3];
    #pragma unroll
    for (int t = 0; t < 3; ++t) {
        col[t] = t * 16 + c16;
        bias[t] = (col[t] < 40) ? bfuse[col[t]] : 0.0f;
        #pragma unroll
        for (int kk = 0; kk < 4; ++kk)
            bfrag[t][kk] = *reinterpret_cast<const bf16x8*>(
                Wfb + col[t] * 128 + kk * 32 + q * 8);
    }

    const int base = blockIdx.x * 64;

    for (int ci = tid; ci < 1024; ci += 256) {
        int r = ci >> 4, c = ci & 15;
        uint4 v = {0, 0, 0, 0};
        if (base + r < n_nodes)
            v = *reinterpret_cast<const uint4*>(hin + (size_t)(base + r) * DD + c * 8);
        *reinterpret_cast<uint4*>(a_s + r * 256 + ((c ^ (r & 7)) * 16)) = v;
    }
    __syncthreads();

    f32x4 acc[3] = {};
    const int arow = w * 16 + c16;
    #pragma unroll
    for (int kk = 0; kk < 4; ++kk) {
        int cc = kk * 4 + q;
        bf16x8 a = *reinterpret_cast<const bf16x8*>(
            a_s + arow * 256 + ((cc ^ (arow & 7)) * 16));
        acc[0] = __builtin_amdgcn_mfma_f32_16x16x32_bf16(a, bfrag[0][kk], acc[0], 0, 0, 0);
        acc[1] = __builtin_amdgcn_mfma_f32_16x16x32_bf16(a, bfrag[1][kk], acc[1], 0, 0, 0);
        acc[2] = __builtin_amdgcn_mfma_f32_16x16x32_bf16(a, bfrag[2][kk], acc[2], 0, 0, 0);
    }

    #pragma unroll
    for (int reg = 0; reg < 4; ++reg) {
        int row = base + w * 16 + q * 4 + reg;
        float v[3];
        float m = -INFINITY;
        #pragma unroll
        for (int t = 0; t < 3; ++t) {
            v[t] = acc[t][reg] + bias[t];
            if (col[t] < 40) m = fmaxf(m, v[t]);
        }
        m = fmaxf(m, __shfl_xor(m, 1));
        m = fmaxf(m, __shfl_xor(m, 2));
        m = fmaxf(m, __shfl_xor(m, 4));
        m = fmaxf(m, __shfl_xor(m, 8));
        float s = 0.0f;
        #pragma unroll
        for (int t = 0; t < 3; ++t)
            if (col[t] < 40) s += expf(v[t] - m);
        s += __shfl_xor(s, 1);
        s += __shfl_xor(s, 2);
        s += __shfl_xor(s, 4);
        s += __shfl_xor(s, 8);
        float lg = logf(s);
        if (row < n_nodes) {
            #pragma unroll
            for (int t = 0; t < 3; ++t)
                if (col[t] < 40)
                    out[(size_t)row * 40 + col[t]] = v[t] - m - lg;
        }
    }
}

// ---------------------------------------------------------------------------
extern "C" void kernel_launch(void* const* d_in, const int* in_sizes, int n_in,
                              void* d_out, int out_size, void* d_ws, size_t ws_size,
                              hipStream_t stream) {
    const float* x   = (const float*)d_in[0];
    const int*   ei  = (const int*)d_in[1];
    const float* Wl  = (const float*)d_in[2];
    const float* bl  = (const float*)d_in[3];
    const float* Wr  = (const float*)d_in[4];
    const float* br  = (const float*)d_in[5];
    const float* W1f = (const float*)d_in[6];
    const float* b1  = (const float*)d_in[7];
    const float* W2  = (const float*)d_in[8];
    const float* b2  = (const float*)d_in[9];
    float* outp = (float*)d_out;

    // Workspace: xb | P(unused) | bufA | bufB | h8 | Wcat | Wfb+bfuse |
    //            cursor | row_ptr | rpe | ssrc(padded) | packed(padded)
    u16* xb   = (u16*)d_ws;
    u16* P    = xb + (size_t)NN * DD;
    u16* bufA = P + (size_t)NN * DD;
    u16* bufB = bufA + (size_t)NN * DD;
    u8*  h8   = (u8*)(bufB + (size_t)NN * DD);
    u16* Wcat = (u16*)(h8 + (size_t)NN * 128);
    u16* Wfb  = Wcat + 3 * 128 * 256;
    float* bfuse = (float*)(Wfb + 8192);
    int* cursor  = (int*)(Wfb + 128 * 128);
    int* row_ptr = cursor + NBUCK + 1;
    int* rpe     = row_ptr + NN;
    int* ssrc    = rpe + NN;
    u32* packed  = (u32*)(ssrc + NBUCK * BUCKCAP);

    // CSR build: fixed-capacity buckets
    initcur_kernel<<<2, 256, 0, stream>>>(cursor);
    bscatter_kernel<<<(NE + SCHUNK - 1) / SCHUNK, 256, 0, stream>>>(
        ei, cursor, packed, NE);
    blocal_kernel<<<NBUCK, 256, 0, stream>>>(packed, cursor, row_ptr, rpe, ssrc);

    // Conversions + algebraic post-fusion precompute
    cvt_x_kernel<<<6250, 256, 0, stream>>>(x, xb, h8, (long long)NN * DD / 8);
    cvt_w_kernel<<<(3 * 128 * 256 + 255) / 256, 256, 0, stream>>>(Wl, Wr, Wcat);
    wfuse_kernel<<<24, 256, 0, stream>>>(W1f, b1, W2, b2, Wfb, bfuse);

    const int n_strips64 = (NN + 63) / 64;   // 1563
    const int n8 = NN * DD / 8;

    const u16* hcur = xb;
    u16* hnext;
    for (int i = 0; i < 3; ++i) {
        hnext = (i == 0) ? bufA : ((hcur == bufA) ? bufB : bufA);
        fused_layer<<<n_strips64, 256, 0, stream>>>(
            hcur, h8, row_ptr, rpe, ssrc, Wcat + (size_t)i * 128 * 256,
            bl + (size_t)i * DD, br + (size_t)i * DD, hnext, NN);
        if (i < 2)   // next layer's gather needs fp8 copy of hnext
            cvt8_kernel<<<2048, 256, 0, stream>>>(hnext, h8, n8);
        hcur = hnext;
    }
    // Fused post1+post2+log_softmax
    postfused_kernel<<<n_strips64, 256, 0, stream>>>(hcur, Wfb, bfuse, outp, NN);
}